// Round 5
// baseline (164.558 us; speedup 1.0000x reference)
//
#include <hip/hip_runtime.h>

// Fused CRF NLL: B=1024, T=2048, K=9 (START=7, STOP=8).
// R5: kill ALL ds_bpermute traffic in the hot recurrence (R4 counters:
// per-SIMD VALU issue only ~15%; duration ~ DS-pipe/latency accounting).
// Each lane of a chunk-group now loads the full 7-float emission row itself
// (8 lanes -> same addresses, coalescer dedups) and computes its own exps:
// zero cross-lane ops per step, recurrence chain = 7-deep FMA only.
// CPS 64->128 (Lb<=16), SLICES=16 -> 4096 blocks = 2x oversubscription for
// dynamic tail refill.
//
// Kernel A (crf_chunk_kernel), B*4 blocks x 256 thr:
//   wave = one SLICE s (8 chunks) of sentence b, W = bid*4+widx, s=W/B, b=W%B.
//   gold partial for slice's t-range; 8 chunk 7x7 linear-space transfer mats
//   (2-step software pipeline, renorm every 2 steps, E in SGPRs);
//   in-wave 8->1 log-matmul fold (7 steps, bpermute -- off the hot loop);
//   segment matrix -> ws.
// Kernel B (crf_fold_kernel), B blocks x 64 thr:
//   stage 16 segment mats, sum 16 gold partials, replicated-alpha fold,
//   STOP readout, atomicAdd((fwd-gold)/B).

#define START_TAG 7
#define STOP_TAG  8
#define KDIM      9
#define NS        7
#define CPS       128         // chunks per sentence
#define SLICES    16          // waves (slices) per sentence
#define NEGINF    (-1e30f)

__device__ __forceinline__ float rfl(float x) {
    return __int_as_float(__builtin_amdgcn_readfirstlane(__float_as_int(x)));
}

// ---------------------------------------------------------------- kernel A --
__global__ __launch_bounds__(256, 4) void crf_chunk_kernel(
    const float* __restrict__ feats,
    const float* __restrict__ trans,
    const int*   __restrict__ tags,
    const int*   __restrict__ lengths,
    float* __restrict__ g_seg,
    float* __restrict__ g_gold,
    int B, int T)
{
    __shared__ float s_trans[81];
    __shared__ float s_E[49];
    __shared__ float s_M[4 * 512];       // per-wave 8 chunk mats [k][j*8+i]

    const int tid = threadIdx.x;
    if (tid < 81) s_trans[tid] = trans[tid];
    if (tid >= 128 && tid < 177) {
        int k = tid - 128;
        s_E[k] = __expf(trans[(k / 7) * 9 + (k % 7)]);
    }
    __syncthreads();

    const int widx = tid >> 6;
    const int W    = blockIdx.x * 4 + widx;     // global wave id in [0, 16B)
    const int s    = W / B;                     // slice 0..15
    const int b    = W - s * B;                 // sentence

    const int    len   = lengths[b];
    const int*   tg    = tags  + (size_t)b * T;
    const float* fbase = feats + (size_t)b * T * KDIM;
    const int    Lb    = (len > 1) ? ((len - 1 + CPS - 1) / CPS) : 1;

    // ---- gold partial for this slice's t-range ----
    {
        const int gs = (s == 0) ? 0 : 1 + s * 8 * Lb;
        const int ge = (s == SLICES - 1) ? len : min(1 + (s + 1) * 8 * Lb, len);
        float g = 0.f;
        if (gs < ge) {
            int span = ge - gs;
            int per  = (span + 63) >> 6;
            int t0   = gs + (tid & 63) * per;
            if (t0 < ge) {
                int te   = min(t0 + per, ge);
                int prev = (t0 == 0) ? START_TAG : tg[t0 - 1];
                for (int k = 0; k < per; ++k) {
                    int t   = t0 + k;
                    int tc  = min(t, te - 1);
                    int cur = tg[tc];
                    float v = s_trans[cur * 9 + prev] + fbase[(size_t)tc * KDIM + cur];
                    g += (t < te) ? v : 0.f;
                    prev = cur;
                }
                if (len - 1 >= t0 && len - 1 < t0 + per && len - 1 < ge)
                    g += s_trans[STOP_TAG * 9 + tg[len - 1]];
            }
        }
        #pragma unroll
        for (int off = 32; off > 0; off >>= 1) g += __shfl_xor(g, off, 64);
        if ((tid & 63) == 0) g_gold[b * SLICES + s] = g;
    }

    // ---- phase 2: 8 chunk matrices, zero cross-lane ops per step ----
    {
        const int lane8  = tid & 7;
        const int k      = (tid >> 3) & 7;      // chunk-in-slice
        const int c      = s * 8 + k;           // global chunk of sentence
        const int tstart = 1 + c * Lb;
        const int tend   = min(tstart + Lb, len);

        if (lane8 < NS) {
            float* Mw = s_M + widx * 512 + k * 64;
            if (tstart < tend) {
                float E[49];
                #pragma unroll
                for (int e = 0; e < 49; ++e) E[e] = rfl(s_E[e]);

                float p[NS];
                #pragma unroll
                for (int j = 0; j < NS; ++j) p[j] = (j == lane8) ? 1.f : 0.f;
                float sc  = 0.f;
                int   rem = tend - tstart;

                // group-shared row pointer (all 8 lanes load same addresses)
                const float* fp = fbase + (size_t)tstart * KDIM;

                #define L7(D, OFF) do {                                         \
                    _Pragma("unroll")                                           \
                    for (int i7 = 0; i7 < NS; ++i7) D[i7] = fp[(OFF) + i7];     \
                } while (0)

                // X = raw feats for this step; exps are lane-local (hoistable,
                // independent of the p-recurrence).
                #define CRF_STEP(X) do {                                        \
                    float q[NS];                                                \
                    _Pragma("unroll")                                           \
                    for (int j = 0; j < NS; ++j) {                              \
                        float acc = E[j * 7] * p[0];                            \
                        _Pragma("unroll")                                       \
                        for (int i = 1; i < NS; ++i)                            \
                            acc = fmaf(E[j * 7 + i], p[i], acc);                \
                        q[j] = acc;                                             \
                    }                                                           \
                    _Pragma("unroll")                                           \
                    for (int j = 0; j < NS; ++j) p[j] = q[j] * __expf(X[j]);    \
                } while (0)

                #define CRF_RENORM() do {                                       \
                    float m = p[0];                                             \
                    _Pragma("unroll")                                           \
                    for (int j = 1; j < NS; ++j) m = fmaxf(m, p[j]);            \
                    float rm = __builtin_amdgcn_rcpf(m);                        \
                    _Pragma("unroll")                                           \
                    for (int j = 0; j < NS; ++j) p[j] *= rm;                    \
                    sc += __logf(m);                                            \
                } while (0)

                float xa[NS], xb[NS];
                L7(xa, 0);
                {
                    int o1 = (rem > 1) ? KDIM : 0;
                    L7(xb, o1);
                }

                while (rem >= 4) {
                    float ya[NS], yb[NS];
                    L7(ya, 2 * KDIM);
                    L7(yb, 3 * KDIM);
                    CRF_STEP(xa);
                    CRF_STEP(xb);
                    CRF_RENORM();
                    #pragma unroll
                    for (int i = 0; i < NS; ++i) { xa[i] = ya[i]; xb[i] = yb[i]; }
                    fp  += 2 * KDIM;
                    rem -= 2;
                }
                // rem in [1,3]
                CRF_STEP(xa);
                if (rem > 1) CRF_STEP(xb);
                if (rem > 2) {
                    float yc[NS];
                    L7(yc, 2 * KDIM);
                    CRF_STEP(yc);
                }

                #pragma unroll
                for (int j = 0; j < NS; ++j)
                    Mw[j * 8 + lane8] = __logf(p[j]) + sc;

                #undef L7
                #undef CRF_STEP
                #undef CRF_RENORM
            } else {
                #pragma unroll
                for (int j = 0; j < NS; ++j)
                    Mw[j * 8 + lane8] = (j == lane8) ? 0.f : NEGINF;
            }
        }
    }

    // same-wave LDS write->read: drain DS queue, fence the compiler.
    asm volatile("s_waitcnt lgkmcnt(0)" ::: "memory");

    // ---- in-wave fold: 8 chunk mats -> 1 segment mat; lane l=j*8+i ----
    {
        const int l  = tid & 63;
        const int i  = l & 7;
        float* sg = s_M + widx * 512;

        float A = sg[l];                         // A = M_{c0}
        int baddr[NS];
        #pragma unroll
        for (int k = 0; k < NS; ++k) baddr[k] = ((k << 3) | i) << 2;

        #pragma unroll
        for (int c = 1; c < 8; ++c) {
            const float* Mr = sg + c * 64 + (l & 56);   // row j of Mc
            float4 r0 = *(const float4*)(Mr);
            float4 r1 = *(const float4*)(Mr + 4);
            float ac[NS];
            #pragma unroll
            for (int k = 0; k < NS; ++k)
                ac[k] = __int_as_float(__builtin_amdgcn_ds_bpermute(
                            baddr[k], __float_as_int(A)));
            float t0 = r0.x + ac[0], t1 = r0.y + ac[1], t2 = r0.z + ac[2];
            float t3 = r0.w + ac[3], t4 = r1.x + ac[4], t5 = r1.y + ac[5];
            float t6 = r1.z + ac[6];
            float tm = fmaxf(fmaxf(fmaxf(t0, t1), fmaxf(t2, t3)),
                             fmaxf(fmaxf(t4, t5), t6));
            float sum = ((__expf(t0 - tm) + __expf(t1 - tm)) +
                         (__expf(t2 - tm) + __expf(t3 - tm))) +
                        ((__expf(t4 - tm) + __expf(t5 - tm)) + __expf(t6 - tm));
            A = tm + __logf(sum);
        }
        // segment matrix out (junk rows/cols j==7 / i==7 land in padding)
        g_seg[((size_t)(b * SLICES + s)) * 64 + l] = A;
    }
}

// ---------------------------------------------------------------- kernel B --
__global__ __launch_bounds__(64) void crf_fold_kernel(
    const float* __restrict__ feats,
    const float* __restrict__ trans,
    const float* __restrict__ g_seg,
    const float* __restrict__ g_gold,
    float* __restrict__ out,
    int B, int T)
{
    __shared__ float s_S[SLICES * 64];   // 16 segment mats, stride 64

    const int tid = threadIdx.x;
    const int b   = blockIdx.x;

    {
        const float* sp = g_seg + (size_t)b * (SLICES * 64);
        #pragma unroll
        for (int k = 0; k < SLICES; ++k) s_S[tid + 64 * k] = sp[tid + 64 * k];
    }
    // sum the 16 gold partials (lanes 0..15)
    float gg = (tid < SLICES) ? g_gold[b * SLICES + tid] : 0.f;
    gg += __shfl_xor(gg, 1, 16);
    gg += __shfl_xor(gg, 2, 16);
    gg += __shfl_xor(gg, 4, 16);
    gg += __shfl_xor(gg, 8, 16);
    __syncthreads();

    if (tid < 8) {
        const int  lane  = tid;
        const bool isrow = (lane < NS);
        const int  row   = isrow ? lane : 0;
        const float* fbase = feats + (size_t)b * T * KDIM;

        float a[NS];
        #pragma unroll
        for (int i = 0; i < NS; ++i)
            a[i] = trans[i * 9 + START_TAG] + fbase[i];
        float S;
        {
            float mm = fmaxf(fmaxf(fmaxf(a[0], a[1]), fmaxf(a[2], a[3])),
                             fmaxf(fmaxf(a[4], a[5]), a[6]));
            S = mm;
            #pragma unroll
            for (int i = 0; i < NS; ++i) a[i] -= mm;
        }

        const float* Mr0 = s_S + row * 8;
        float4 mA = *(const float4*)(Mr0);
        float4 mB = *(const float4*)(Mr0 + 4);
        #pragma unroll
        for (int w = 0; w < SLICES; ++w) {
            int wn = min(w + 1, SLICES - 1);
            float4 nA = *(const float4*)(Mr0 + wn * 64);
            float4 nB = *(const float4*)(Mr0 + wn * 64 + 4);
            float t0 = mA.x + a[0], t1 = mA.y + a[1], t2 = mA.z + a[2];
            float t3 = mA.w + a[3], t4 = mB.x + a[4], t5 = mB.y + a[5];
            float t6 = mB.z + a[6];
            float tm = fmaxf(fmaxf(fmaxf(t0, t1), fmaxf(t2, t3)),
                             fmaxf(fmaxf(t4, t5), t6));
            float e0 = __expf(t0 - tm), e1 = __expf(t1 - tm), e2 = __expf(t2 - tm);
            float e3 = __expf(t3 - tm), e4 = __expf(t4 - tm), e5 = __expf(t5 - tm);
            float e6 = __expf(t6 - tm);
            float sum = ((e0 + e1) + (e2 + e3)) + ((e4 + e5) + e6);
            float na = isrow ? (tm + __logf(sum)) : NEGINF;
            float b0 = __shfl(na, 0, 8), b1 = __shfl(na, 1, 8), b2 = __shfl(na, 2, 8);
            float b3 = __shfl(na, 3, 8), b4 = __shfl(na, 4, 8), b5 = __shfl(na, 5, 8);
            float b6 = __shfl(na, 6, 8);
            float mm = fmaxf(fmaxf(fmaxf(b0, b1), fmaxf(b2, b3)),
                             fmaxf(fmaxf(b4, b5), b6));
            a[0] = b0 - mm; a[1] = b1 - mm; a[2] = b2 - mm;
            a[3] = b3 - mm; a[4] = b4 - mm; a[5] = b5 - mm;
            a[6] = b6 - mm;
            S += mm;
            mA = nA; mB = nB;
        }

        if (lane == 0) {
            float t0 = a[0] + trans[STOP_TAG * 9 + 0];
            float t1 = a[1] + trans[STOP_TAG * 9 + 1];
            float t2 = a[2] + trans[STOP_TAG * 9 + 2];
            float t3 = a[3] + trans[STOP_TAG * 9 + 3];
            float t4 = a[4] + trans[STOP_TAG * 9 + 4];
            float t5 = a[5] + trans[STOP_TAG * 9 + 5];
            float t6 = a[6] + trans[STOP_TAG * 9 + 6];
            float tm = fmaxf(fmaxf(fmaxf(t0, t1), fmaxf(t2, t3)),
                             fmaxf(fmaxf(t4, t5), t6));
            float sum = ((__expf(t0 - tm) + __expf(t1 - tm)) +
                         (__expf(t2 - tm) + __expf(t3 - tm))) +
                        ((__expf(t4 - tm) + __expf(t5 - tm)) + __expf(t6 - tm));
            float fwd = S + tm + __logf(sum);
            atomicAdd(out, (fwd - gg) * (1.0f / (float)B));
        }
    }
}

__global__ void init_out_kernel(float* out) {
    if (threadIdx.x == 0) out[0] = 0.f;
}

extern "C" void kernel_launch(void* const* d_in, const int* in_sizes, int n_in,
                              void* d_out, int out_size, void* d_ws, size_t ws_size,
                              hipStream_t stream) {
    const float* feats   = (const float*)d_in[0];
    const float* trans   = (const float*)d_in[1];
    const int*   tags    = (const int*)d_in[2];
    const int*   lengths = (const int*)d_in[3];

    int B = in_sizes[3];
    int T = in_sizes[2] / B;

    float* seg  = (float*)d_ws;                         // B*16*64 floats = 4 MB
    float* gold = seg + (size_t)B * SLICES * 64;        // B*16 floats = 64 KB

    init_out_kernel<<<1, 64, 0, stream>>>((float*)d_out);
    crf_chunk_kernel<<<B * SLICES / 4, 256, 0, stream>>>(
        feats, trans, tags, lengths, seg, gold, B, T);
    crf_fold_kernel<<<B, 64, 0, stream>>>(
        feats, trans, seg, gold, (float*)d_out, B, T);
}

// Round 6
// 143.094 us; speedup vs baseline: 1.1500x; 1.1500x over previous
//
#include <hip/hip_runtime.h>

// Fused CRF NLL: B=1024, T=2048, K=9 (START=7, STOP=8).
// R6: FUSED single kernel again (workspace use triggers ~46us/iter 302MB
// re-poison fills -- R3/R5 counters; R2-fused remains bench-best).
// Inner loop = R4's issue-optimal sharing (1 exp amortized across 7 lanes +
// 7 ds_bpermute/step) but with the ef broadcast SOFTWARE-PIPELINED one step
// ahead and pinned with sched_barrier(0) so the compiler cannot sink it back
// next to its MAT (R4 VGPR=40 proved the source-level hoist was undone):
// step t's 56-FMA MAT now covers step t+1's DS round-trip.
// setprio(1) around the MAT (desynchronized waves -> the regime where it
// measured positive).
//
// One block per sentence, 512 thr = 8 waves = 64 chunk-groups x 8 lanes.
// Phase 1: gold score, data-parallel (4 t/thread), per-wave reduce.
// Phase 2: per-chunk 7x7 linear-space transfer matrix, 1 lane per column;
//   dynamic Lb = ceil((len-1)/64) (<=32 serial steps); E in SGPRs; lane l
//   loads only f[t][l]; renorm every 4 steps (growth ~1e17, fp32-safe).
// Phase 3a: per-wave 8->1 log-matmul fold (7 steps, lane(j,i) layout).
// Phase 3b: threads 0..7 fold 8 segment mats with replicated alpha,
//   STOP readout, atomicAdd((fwd-gold)/B).

#define START_TAG 7
#define STOP_TAG  8
#define KDIM      9
#define NS        7
#define CHUNKS    64
#define NEGINF    (-1e30f)

__device__ __forceinline__ float rfl(float x) {
    return __int_as_float(__builtin_amdgcn_readfirstlane(__float_as_int(x)));
}

__global__ __launch_bounds__(512, 4) void crf_fused_kernel(
    const float* __restrict__ feats,
    const float* __restrict__ trans,
    const int*   __restrict__ tags,
    const int*   __restrict__ lengths,
    float* __restrict__ out,
    int B, int T)
{
    __shared__ float s_trans[81];
    __shared__ float s_E[49];
    __shared__ float s_M[CHUNKS * 64];   // [c][j*8 + i] rows padded to 8
    __shared__ float s_gold[8];

    const int tid = threadIdx.x;
    const int b   = blockIdx.x;

    if (tid < 81) s_trans[tid] = trans[tid];
    if (tid >= 128 && tid < 177) {
        int k = tid - 128;
        s_E[k] = __expf(trans[(k / 7) * 9 + (k % 7)]);
    }
    __syncthreads();

    const int    len   = lengths[b];
    const int*   tg    = tags  + (size_t)b * T;
    const float* fbase = feats + (size_t)b * T * KDIM;
    const int    Lb    = (len > 1) ? ((len - 1 + CHUNKS - 1) / CHUNKS) : 1;

    // ---------------- phase 1: gold score ----------------
    {
        int per = T >> 9; if (per < 1) per = 1;   // 4 for T=2048
        int t0  = tid * per;
        float g = 0.f;
        if (t0 < len) {
            int te   = min(t0 + per, len);
            int prev = (t0 == 0) ? START_TAG : tg[t0 - 1];
            if (per == 4) {
                #pragma unroll
                for (int k = 0; k < 4; ++k) {
                    int t   = t0 + k;
                    int tc  = min(t, te - 1);
                    int cur = tg[tc];
                    float v = s_trans[cur * 9 + prev] + fbase[(size_t)tc * KDIM + cur];
                    g += (t < te) ? v : 0.f;
                    prev = cur;
                }
            } else {
                for (int k = 0; k < per; ++k) {
                    int t   = t0 + k;
                    int tc  = min(t, te - 1);
                    int cur = tg[tc];
                    float v = s_trans[cur * 9 + prev] + fbase[(size_t)tc * KDIM + cur];
                    g += (t < te) ? v : 0.f;
                    prev = cur;
                }
            }
            if (len - 1 >= t0 && len - 1 < t0 + per)
                g += s_trans[STOP_TAG * 9 + tg[len - 1]];
        }
        #pragma unroll
        for (int off = 32; off > 0; off >>= 1) g += __shfl_xor(g, off, 64);
        if ((tid & 63) == 0) s_gold[tid >> 6] = g;
    }

    // ---------------- phase 2: chunk matrices ----------------
    {
        const int lane8  = tid & 7;
        const int c      = tid >> 3;             // 0..63
        const int tstart = 1 + c * Lb;
        const int tend   = min(tstart + Lb, len);

        if (lane8 < NS) {
            float* Mw = s_M + c * 64;
            if (tstart < tend) {
                float E[49];
                #pragma unroll
                for (int e = 0; e < 49; ++e) E[e] = rfl(s_E[e]);

                // bpermute byte addresses: group base within wave | j
                int baddr[NS];
                #pragma unroll
                for (int j = 0; j < NS; ++j) baddr[j] = (((tid & 56) | j) << 2);

                float p[NS];
                #pragma unroll
                for (int j = 0; j < NS; ++j) p[j] = (j == lane8) ? 1.f : 0.f;
                float s = 0.f;
                int rem = tend - tstart;

                const float* fp = fbase + (size_t)tstart * KDIM + lane8;

                #define CRF_MAT(EF) do {                                        \
                    float q[NS];                                                \
                    _Pragma("unroll")                                           \
                    for (int j = 0; j < NS; ++j) {                              \
                        float acc = E[j * 7] * p[0];                            \
                        _Pragma("unroll")                                       \
                        for (int i = 1; i < NS; ++i)                            \
                            acc = fmaf(E[j * 7 + i], p[i], acc);                \
                        q[j] = acc;                                             \
                    }                                                           \
                    _Pragma("unroll")                                           \
                    for (int j = 0; j < NS; ++j) p[j] = q[j] * EF[j];           \
                } while (0)

                #define CRF_BCAST(DST, XF) do {                                 \
                    float _e = __expf(XF);                                      \
                    _Pragma("unroll")                                           \
                    for (int j = 0; j < NS; ++j)                                \
                        DST[j] = __int_as_float(                                \
                            __builtin_amdgcn_ds_bpermute(                       \
                                baddr[j], __float_as_int(_e)));                 \
                } while (0)

                // pipelined: issue NEXT step's bcast, fence so it cannot sink
                // below this step's MAT, then run this step's MAT (DS latency
                // hides under 56 FMA of issue).
                #define CRF_PSTEP(EFN, XN, EFC) do {                            \
                    CRF_BCAST(EFN, XN);                                         \
                    __builtin_amdgcn_sched_barrier(0);                          \
                    __builtin_amdgcn_s_setprio(1);                              \
                    CRF_MAT(EFC);                                               \
                    __builtin_amdgcn_s_setprio(0);                              \
                } while (0)

                #define CRF_STEP(XF) do {                                       \
                    float _ef[NS];                                              \
                    CRF_BCAST(_ef, XF);                                         \
                    CRF_MAT(_ef);                                               \
                } while (0)

                #define CRF_RENORM() do {                                       \
                    float m = p[0];                                             \
                    _Pragma("unroll")                                           \
                    for (int j = 1; j < NS; ++j) m = fmaxf(m, p[j]);            \
                    float rm = __builtin_amdgcn_rcpf(m);                        \
                    _Pragma("unroll")                                           \
                    for (int j = 0; j < NS; ++j) p[j] *= rm;                    \
                    s += __logf(m);                                             \
                } while (0)

                // initial preload (clamped so short chunks never read OOB)
                int o1 = KDIM * min(1, rem - 1);
                int o2 = KDIM * min(2, rem - 1);
                int o3 = KDIM * min(3, rem - 1);
                float x0 = fp[0], x1 = fp[o1], x2 = fp[o2], x3 = fp[o3];
                fp += 4 * KDIM;

                float ef0[NS];
                CRF_BCAST(ef0, x0);              // prime the ef pipeline

                while (rem >= 8) {
                    float y0 = fp[0], y1 = fp[KDIM], y2 = fp[2 * KDIM], y3 = fp[3 * KDIM];
                    fp += 4 * KDIM;
                    float ef1[NS], ef2[NS], ef3[NS], ef4[NS];
                    CRF_PSTEP(ef1, x1, ef0);
                    CRF_PSTEP(ef2, x2, ef1);
                    CRF_PSTEP(ef3, x3, ef2);
                    CRF_PSTEP(ef4, y0, ef3);     // y0 = next group's x0
                    CRF_RENORM();
                    #pragma unroll
                    for (int j = 0; j < NS; ++j) ef0[j] = ef4[j];
                    x0 = y0; x1 = y1; x2 = y2; x3 = y3;
                    rem -= 4;
                }
                if (rem > 4) {                   // rem in [5,7]
                    int e1 = KDIM * min(1, rem - 5);
                    int e2 = KDIM * min(2, rem - 5);
                    float y0 = fp[0], y1 = fp[e1], y2 = fp[e2];
                    float ef1[NS], ef2[NS], ef3[NS], ef4[NS];
                    CRF_PSTEP(ef1, x1, ef0);
                    CRF_PSTEP(ef2, x2, ef1);
                    CRF_PSTEP(ef3, x3, ef2);
                    CRF_PSTEP(ef4, y0, ef3);
                    CRF_RENORM();
                    #pragma unroll
                    for (int j = 0; j < NS; ++j) ef0[j] = ef4[j];
                    x0 = y0; x1 = y1; x2 = y2;
                    rem -= 4;
                }
                // rem in [1,4]; ef0 corresponds to x0
                CRF_MAT(ef0);
                if (rem > 1) CRF_STEP(x1);
                if (rem > 2) CRF_STEP(x2);
                if (rem > 3) CRF_STEP(x3);

                #pragma unroll
                for (int j = 0; j < NS; ++j)
                    Mw[j * 8 + lane8] = __logf(p[j]) + s;

                #undef CRF_MAT
                #undef CRF_BCAST
                #undef CRF_PSTEP
                #undef CRF_STEP
                #undef CRF_RENORM
            } else {
                #pragma unroll
                for (int j = 0; j < NS; ++j)
                    Mw[j * 8 + lane8] = (j == lane8) ? 0.f : NEGINF;
            }
        }
    }

    // same-wave LDS write->read: drain DS queue, fence the compiler.
    asm volatile("s_waitcnt lgkmcnt(0)" ::: "memory");

    // ------- phase 3a: per-wave segment fold (8 chunk mats -> 1 per wave) ----
    // wave w folds chunks 8w..8w+7 (written by its own lanes). lane l=j*8+i.
    {
        const int l = tid & 63;
        const int w = tid >> 6;
        const int i = l & 7;
        float* seg = s_M + w * 512;          // 8 chunks x 64 floats

        float A = seg[l];                     // A = M_{8w}
        int baddr[NS];
        #pragma unroll
        for (int k = 0; k < NS; ++k) baddr[k] = ((k << 3) | i) << 2;

        #pragma unroll
        for (int c = 1; c < 8; ++c) {
            const float* Mr = seg + c * 64 + (l & 56);   // row j of Mc
            float4 r0 = *(const float4*)(Mr);
            float4 r1 = *(const float4*)(Mr + 4);
            float ac[NS];
            #pragma unroll
            for (int k = 0; k < NS; ++k)
                ac[k] = __int_as_float(__builtin_amdgcn_ds_bpermute(
                            baddr[k], __float_as_int(A)));
            float t0 = r0.x + ac[0], t1 = r0.y + ac[1], t2 = r0.z + ac[2];
            float t3 = r0.w + ac[3], t4 = r1.x + ac[4], t5 = r1.y + ac[5];
            float t6 = r1.z + ac[6];
            float tm = fmaxf(fmaxf(fmaxf(t0, t1), fmaxf(t2, t3)),
                             fmaxf(fmaxf(t4, t5), t6));
            float sum = ((__expf(t0 - tm) + __expf(t1 - tm)) +
                         (__expf(t2 - tm) + __expf(t3 - tm))) +
                        ((__expf(t4 - tm) + __expf(t5 - tm)) + __expf(t6 - tm));
            A = tm + __logf(sum);
        }
        seg[l] = A;   // segment matrix; junk rows/cols land in padding slots
    }
    __syncthreads();

    // ------- phase 3b: fold 8 segment matrices with replicated alpha --------
    if (tid < 8) {
        const int  lane  = tid;
        const bool isrow = (lane < NS);
        const int  row   = isrow ? lane : 0;

        float a[NS];
        #pragma unroll
        for (int i = 0; i < NS; ++i)
            a[i] = s_trans[i * 9 + START_TAG] + fbase[i];
        float S;
        {
            float mm = fmaxf(fmaxf(fmaxf(a[0], a[1]), fmaxf(a[2], a[3])),
                             fmaxf(fmaxf(a[4], a[5]), a[6]));
            S = mm;
            #pragma unroll
            for (int i = 0; i < NS; ++i) a[i] -= mm;
        }

        const float* Mr0 = s_M + row * 8;
        float4 mA = *(const float4*)(Mr0);
        float4 mB = *(const float4*)(Mr0 + 4);
        #pragma unroll
        for (int w = 0; w < 8; ++w) {
            int wn = min(w + 1, 7);
            float4 nA = *(const float4*)(Mr0 + wn * 512);
            float4 nB = *(const float4*)(Mr0 + wn * 512 + 4);
            float t0 = mA.x + a[0], t1 = mA.y + a[1], t2 = mA.z + a[2];
            float t3 = mA.w + a[3], t4 = mB.x + a[4], t5 = mB.y + a[5];
            float t6 = mB.z + a[6];
            float tm = fmaxf(fmaxf(fmaxf(t0, t1), fmaxf(t2, t3)),
                             fmaxf(fmaxf(t4, t5), t6));
            float e0 = __expf(t0 - tm), e1 = __expf(t1 - tm), e2 = __expf(t2 - tm);
            float e3 = __expf(t3 - tm), e4 = __expf(t4 - tm), e5 = __expf(t5 - tm);
            float e6 = __expf(t6 - tm);
            float sum = ((e0 + e1) + (e2 + e3)) + ((e4 + e5) + e6);
            float na = isrow ? (tm + __logf(sum)) : NEGINF;
            float b0 = __shfl(na, 0, 8), b1 = __shfl(na, 1, 8), b2 = __shfl(na, 2, 8);
            float b3 = __shfl(na, 3, 8), b4 = __shfl(na, 4, 8), b5 = __shfl(na, 5, 8);
            float b6 = __shfl(na, 6, 8);
            float mm = fmaxf(fmaxf(fmaxf(b0, b1), fmaxf(b2, b3)),
                             fmaxf(fmaxf(b4, b5), b6));
            a[0] = b0 - mm; a[1] = b1 - mm; a[2] = b2 - mm;
            a[3] = b3 - mm; a[4] = b4 - mm; a[5] = b5 - mm;
            a[6] = b6 - mm;
            S += mm;
            mA = nA; mB = nB;
        }

        if (lane == 0) {
            float t0 = a[0] + s_trans[STOP_TAG * 9 + 0];
            float t1 = a[1] + s_trans[STOP_TAG * 9 + 1];
            float t2 = a[2] + s_trans[STOP_TAG * 9 + 2];
            float t3 = a[3] + s_trans[STOP_TAG * 9 + 3];
            float t4 = a[4] + s_trans[STOP_TAG * 9 + 4];
            float t5 = a[5] + s_trans[STOP_TAG * 9 + 5];
            float t6 = a[6] + s_trans[STOP_TAG * 9 + 6];
            float tm = fmaxf(fmaxf(fmaxf(t0, t1), fmaxf(t2, t3)),
                             fmaxf(fmaxf(t4, t5), t6));
            float sum = ((__expf(t0 - tm) + __expf(t1 - tm)) +
                         (__expf(t2 - tm) + __expf(t3 - tm))) +
                        ((__expf(t4 - tm) + __expf(t5 - tm)) + __expf(t6 - tm));
            float fwd = S + tm + __logf(sum);
            float g = (s_gold[0] + s_gold[1] + s_gold[2] + s_gold[3]) +
                      (s_gold[4] + s_gold[5] + s_gold[6] + s_gold[7]);
            atomicAdd(out, (fwd - g) * (1.0f / (float)B));
        }
    }
}

__global__ void init_out_kernel(float* out) {
    if (threadIdx.x == 0) out[0] = 0.f;
}

extern "C" void kernel_launch(void* const* d_in, const int* in_sizes, int n_in,
                              void* d_out, int out_size, void* d_ws, size_t ws_size,
                              hipStream_t stream) {
    const float* feats   = (const float*)d_in[0];
    const float* trans   = (const float*)d_in[1];
    const int*   tags    = (const int*)d_in[2];
    const int*   lengths = (const int*)d_in[3];

    int B = in_sizes[3];
    int T = in_sizes[2] / B;

    init_out_kernel<<<1, 64, 0, stream>>>((float*)d_out);
    crf_fused_kernel<<<B, 512, 0, stream>>>(
        feats, trans, tags, lengths, (float*)d_out, B, T);
}